// Round 6
// baseline (106.839 us; speedup 1.0000x reference)
//
#include <hip/hip_runtime.h>

namespace {
constexpr int kN = 8192, kV = 8, kO = 16, kH = 128;
constexpr float kStep = 2.0f;
constexpr float kDistCost = 1.0f, kObstCost = 0.1f, kObstRadius = 1.0f;
constexpr float kVehCost = 0.1f, kVehRadius = 1.0f;
constexpr int kInRow = 4 * kV + 3 * kO;  // 80 floats per n
constexpr float kInv2Pi = 0.15915494309189535f;
}  // namespace

typedef float v2f __attribute__((ext_vector_type(2)));

__device__ __forceinline__ float rfl_f(float x) {
  return __int_as_float(__builtin_amdgcn_readfirstlane(__float_as_int(x)));
}

template <int Ctrl, int RowMask, bool Bctrl>
__device__ __forceinline__ float dpp_mov0(float x) {
  return __int_as_float(__builtin_amdgcn_update_dpp(
      0, __float_as_int(x), Ctrl, RowMask, 0xf, Bctrl));
}

// Wave64 inclusive scan on the VALU pipe. Lane 63 holds the wave total.
__device__ __forceinline__ float wave_incl_scan(float x) {
  x += dpp_mov0<0x111, 0xf, true>(x);   // row_shr:1
  x += dpp_mov0<0x112, 0xf, true>(x);   // row_shr:2
  x += dpp_mov0<0x114, 0xf, true>(x);   // row_shr:4
  x += dpp_mov0<0x118, 0xf, true>(x);   // row_shr:8
  x += dpp_mov0<0x142, 0xa, false>(x);  // row_bcast:15 -> rows 1,3
  x += dpp_mov0<0x143, 0xc, false>(x);  // row_bcast:31 -> rows 2,3
  return x;
}

// One block (512 threads = 8 waves) per n.
// Trajectory/term1/term3: wave w = vehicle w, lane l owns h = 2l, 2l+1
// (pair-sum scan keeps the 128-step cumsum fully in-wave).
// Term2 (R6): re-mapped so wave w owns h-window [16w, 16w+16) across ALL
// vehicles (trajectory re-read from LDS). Points in a window are spatially
// coherent (x-drift ~1.2h), so a conservative wave-uniform test
// |p|^2 < R^2, R = max_o(|o|+rr_o) (triangle inequality) skips all 16
// obstacles for far windows — typically 6 of 8 waves skip the whole loop.
__global__ __launch_bounds__(512) void loss_main(
    const float* __restrict__ pred, const float* __restrict__ inputs,
    float* __restrict__ partials) {
  const int n = blockIdx.x;
  const int tid = threadIdx.x;
  const int lane = tid & 63;
  const int w = __builtin_amdgcn_readfirstlane(tid >> 6);  // wave id
  const int v = w;  // vehicle for traj/term1/term3 phases

  const float* __restrict__ row = inputs + (size_t)n * kInRow;

  // Point-pair major trajectory: sh_p[v*65 + k] = (x,y,x,y) for h=2k,2k+1.
  // Row stride 65 float4 -> term2 window reads and term3 reads are
  // bank-balanced (start bank 4*(v2+j) mod 32, exactly 8 lanes per class).
  __shared__ float4 sh_p[kV * 65];
  __shared__ float sh_red[kV][5];

  // Block-uniform obstacle + vehicle data -> scalar loads / SGPRs.
  float ox[kO], oy[kO], rr2[kO];
  float R = 0.f;
#pragma unroll
  for (int o = 0; o < kO; ++o) {
    ox[o] = rfl_f(row[4 * kV + 3 * o + 0]);
    oy[o] = rfl_f(row[4 * kV + 3 * o + 1]);
    float rr = row[4 * kV + 3 * o + 2] + kObstRadius;
    // negative sentinel: d >= 0 can never be < a nonpositive radius
    rr2[o] = rfl_f(rr > 0.f ? rr * rr : -1.0f);
    float co = __builtin_amdgcn_sqrtf(fmaf(oy[o], oy[o], ox[o] * ox[o]));
    R = fmaxf(R, rr > 0.f ? co + rr : 0.f);
  }
  R *= 1.0009765625f;  // conservative +2^-10 slack for fp rounding
  const float R2 = rfl_f(R * R);

  const float vx = rfl_f(row[4 * v + 0]);
  const float vy = rfl_f(row[4 * v + 1]);
  const float tx = rfl_f(row[4 * v + 2]);
  const float ty = rfl_f(row[4 * v + 3]);

  // Two headings per lane; 4 trans ops (unavoidable).
  const float2 th = ((const float2*)(pred + (size_t)n * (kV * kH)))[tid];
  v2f r01 = {th.x, th.y};
  r01 *= kInv2Pi;
  float c0 = __builtin_amdgcn_cosf(r01.x);
  float s0 = __builtin_amdgcn_sinf(r01.x);
  float c1 = __builtin_amdgcn_cosf(r01.y);
  float s1w = __builtin_amdgcn_sinf(r01.y);
  v2f step1 = {c1, s1w};  // step at h=2l+1
  step1 *= kStep;

  // Pair-sum scan: inclusive cumsum through h=2l+1.
  float Sx = wave_incl_scan((c0 + c1) * kStep);
  float Sy = wave_incl_scan((s0 + s1w) * kStep);
  const float px1 = vx + Sx, py1 = vy + Sy;              // h = 2l+1
  const float px0 = px1 - step1.x, py0 = py1 - step1.y;  // h = 2l

  sh_p[v * 65 + lane] = make_float4(px0, py0, px1, py1);

  const v2f pxp = {px0, px1};
  const v2f pyp = {py0, py1};

  // Term 1: distance to target (both points), packed diffs/squares.
  v2f t_dx = tx - pxp;
  v2f t_dy = ty - pyp;
  v2f t_d2 = __builtin_elementwise_fma(t_dy, t_dy, t_dx * t_dx);
  float s1 = __builtin_amdgcn_sqrtf(t_d2.x) + __builtin_amdgcn_sqrtf(t_d2.y);

  __syncthreads();  // sh_p visible

  // Term 3: inter-vehicle distance (v vs v+1, same h). v wave-uniform.
  float s3 = 0.f;
  int c3i = 0;
  if (v < kV - 1) {
    float4 t2 = sh_p[(v + 1) * 65 + lane];
    v2f ex = {t2.x, t2.z};
    v2f ey = {t2.y, t2.w};
    ex -= pxp;
    ey -= pyp;
    v2f e2 = __builtin_elementwise_fma(ey, ey, ex * ex);
    bool m0 = e2.x < kVehRadius * kVehRadius;
    bool m1 = e2.y < kVehRadius * kVehRadius;
    unsigned long long b0 = __ballot(m0);
    unsigned long long b1 = __ballot(m1);
    if (b0 | b1) {
      float i0 = __builtin_amdgcn_rsqf(e2.x);
      float i1 = __builtin_amdgcn_rsqf(e2.y);
      s3 = (m0 ? i0 : 0.f) + (m1 ? i1 : 0.f);
      c3i = (int)__popcll(b0) + (int)__popcll(b1);
    }
  }

  // Term 2 (h-window layout): lane = (v2, j); points h = 16w+2j, 16w+2j+1.
  const int v2i = lane >> 3;
  const int j = lane & 7;
  float4 q = sh_p[v2i * 65 + w * 8 + j];
  const v2f qx = {q.x, q.z};
  const v2f qy = {q.y, q.w};
  float s2 = 0.f;
  int c2i = 0;
  v2f q2 = __builtin_elementwise_fma(qy, qy, qx * qx);
  bool near = (q2.x < R2) || (q2.y < R2);
  if (__ballot(near)) {
#pragma unroll
    for (int o = 0; o < kO; ++o) {
      v2f dx = qx - ox[o];
      v2f dy = qy - oy[o];
      v2f d2 = __builtin_elementwise_fma(dy, dy, dx * dx);
      bool ma = d2.x < rr2[o];
      bool mb = d2.y < rr2[o];
      unsigned long long ba = __ballot(ma);
      unsigned long long bb = __ballot(mb);
      if (ba | bb) {
        float inva = __builtin_amdgcn_rsqf(d2.x);
        float invb = __builtin_amdgcn_rsqf(d2.y);
        s2 += (ma ? inva : 0.f) + (mb ? invb : 0.f);
        c2i += (int)__popcll(ba) + (int)__popcll(bb);
      }
    }
  }

  // Wave-reduce the 3 float sums (counts already wave-scalar), then 8 waves
  // combine through LDS; 5 threads store the block partials.
  float r1s = wave_incl_scan(s1);
  float r2s = wave_incl_scan(s2);
  float r3s = wave_incl_scan(s3);
  if (lane == 63) {
    sh_red[w][0] = r1s;
    sh_red[w][1] = r2s;
    sh_red[w][2] = r3s;
    sh_red[w][3] = (float)c2i;
    sh_red[w][4] = (float)c3i;
  }
  __syncthreads();
  if (tid < 5) {
    float acc = 0.f;
#pragma unroll
    for (int k = 0; k < kV; ++k) acc += sh_red[k][tid];
    partials[tid * kN + n] = acc;  // coalesced across blocks per-array
  }
}

// Single-block tree reduction over kN partials per accumulator (float4 loads).
__global__ __launch_bounds__(1024) void loss_final(
    const float* __restrict__ partials, float* __restrict__ out) {
  const int tid = threadIdx.x;
  const int lane = tid & 63;
  const int wave = tid >> 6;
  __shared__ float sh[16][5];
  float acc[5];
#pragma unroll
  for (int a = 0; a < 5; ++a) {
    const float4* pa = (const float4*)(partials + a * kN);  // 2048 float4
    float4 u = pa[tid];
    float4 w = pa[tid + 1024];
    acc[a] = (u.x + u.y) + (u.z + u.w) + (w.x + w.y) + (w.z + w.w);
  }
#pragma unroll
  for (int a = 0; a < 5; ++a) acc[a] = wave_incl_scan(acc[a]);
  if (lane == 63) {
#pragma unroll
    for (int a = 0; a < 5; ++a) sh[wave][a] = acc[a];
  }
  __syncthreads();
  if (tid == 0) {
    float t[5];
#pragma unroll
    for (int a = 0; a < 5; ++a) {
      float s = 0.f;
#pragma unroll
      for (int k = 0; k < 16; ++k) s += sh[k][a];
      t[a] = s;
    }
    float loss = t[0] * (1.0f / (float)(kN * kV * kH)) * kDistCost;
    if (t[3] > 0.f) loss += (t[1] / t[3]) * kObstCost;
    if (t[4] > 0.f) loss += (t[2] / t[4]) * kVehCost;
    out[0] = loss;
  }
}

extern "C" void kernel_launch(void* const* d_in, const int* in_sizes, int n_in,
                              void* d_out, int out_size, void* d_ws, size_t ws_size,
                              hipStream_t stream) {
  const float* pred = (const float*)d_in[0];     // (N, V, H, 1) f32
  const float* inputs = (const float*)d_in[1];   // (N, 80) f32
  float* partials = (float*)d_ws;                // 5 * kN floats
  loss_main<<<kN, 512, 0, stream>>>(pred, inputs, partials);
  loss_final<<<1, 1024, 0, stream>>>(partials, (float*)d_out);
}

// Round 7
// 96.437 us; speedup vs baseline: 1.1079x; 1.1079x over previous
//
#include <hip/hip_runtime.h>

namespace {
constexpr int kN = 8192, kV = 8, kO = 16, kH = 128;
constexpr float kStep = 2.0f;
constexpr float kDistCost = 1.0f, kObstCost = 0.1f, kObstRadius = 1.0f;
constexpr float kVehCost = 0.1f, kVehRadius = 1.0f;
constexpr int kInRow = 4 * kV + 3 * kO;  // 80 floats per n
constexpr float kInv2Pi = 0.15915494309189535f;
constexpr int kPreStride = 64;  // floats per n in the precomputed record
}  // namespace

typedef float v2f __attribute__((ext_vector_type(2)));

__device__ __forceinline__ float rfl_f(float x) {
  return __int_as_float(__builtin_amdgcn_readfirstlane(__float_as_int(x)));
}

template <int Ctrl, int RowMask, bool Bctrl>
__device__ __forceinline__ float dpp_mov0(float x) {
  return __int_as_float(__builtin_amdgcn_update_dpp(
      0, __float_as_int(x), Ctrl, RowMask, 0xf, Bctrl));
}

// Wave64 inclusive scan on the VALU pipe. Lane 63 holds the wave total.
__device__ __forceinline__ float wave_incl_scan(float x) {
  x += dpp_mov0<0x111, 0xf, true>(x);   // row_shr:1
  x += dpp_mov0<0x112, 0xf, true>(x);   // row_shr:2
  x += dpp_mov0<0x114, 0xf, true>(x);   // row_shr:4
  x += dpp_mov0<0x118, 0xf, true>(x);   // row_shr:8
  x += dpp_mov0<0x142, 0xa, false>(x);  // row_bcast:15 -> rows 1,3
  x += dpp_mov0<0x143, 0xc, false>(x);  // row_bcast:31 -> rows 2,3
  return x;
}

// R7: hoist ALL block-uniform obstacle prep out of loss_main (R6 lesson: the
// rr2 sentinel + prefilter-radius math was ~162 uniform-VALU slots replicated
// per thread — CDNA scalar pipe has no FP, uniform FP burns VALU issue).
// One 16-lane row per n: record = [ox*16, oy*16, rr2*16, R2, pad] (64 floats).
// Prefilter bound uses L1 norm (|ox|+|oy| >= |o|_2): conservative, sqrt-free.
__global__ __launch_bounds__(256) void obst_pre(
    const float* __restrict__ inputs, float* __restrict__ pre) {
  const int t = blockIdx.x * 256 + threadIdx.x;  // kN*16 threads
  const int n = t >> 4;
  const int o = t & 15;
  const float* __restrict__ od = inputs + (size_t)n * kInRow + 4 * kV;
  float x = od[3 * o + 0];
  float y = od[3 * o + 1];
  float rr = od[3 * o + 2] + kObstRadius;
  bool ok = rr > 0.f;  // d >= 0 can never be < a nonpositive radius
  float rr2 = ok ? rr * rr : -1.0f;
  float b = ok ? fabsf(x) + fabsf(y) + rr : 0.f;
  // Inclusive max over the 16-lane row (one n per row); 0-fill is safe (b>=0).
  b = fmaxf(b, dpp_mov0<0x111, 0xf, true>(b));
  b = fmaxf(b, dpp_mov0<0x112, 0xf, true>(b));
  b = fmaxf(b, dpp_mov0<0x114, 0xf, true>(b));
  b = fmaxf(b, dpp_mov0<0x118, 0xf, true>(b));
  float* dst = pre + (size_t)n * kPreStride;
  dst[o] = x;
  dst[16 + o] = y;
  dst[32 + o] = rr2;
  if (o == 15) {
    float R = b * 1.0009765625f;  // +2^-10 slack for fp rounding
    dst[48] = R * R;
  }
}

// One block (512 threads = 8 waves) per n.
// Trajectory/term1/term3: wave w = vehicle w, lane l owns h = 2l, 2l+1
// (pair-sum scan keeps the 128-step cumsum fully in-wave).
// Term2: wave w owns h-window [16w, 16w+16) across ALL vehicles (traj from
// LDS); far windows (x-drift ~1.2h) skip all 16 obstacles via one
// wave-uniform |p|^2 < R^2 test (triangle inequality, R precomputed).
__global__ __launch_bounds__(512) void loss_main(
    const float* __restrict__ pred, const float* __restrict__ inputs,
    const float* __restrict__ pre, float* __restrict__ partials) {
  const int n = blockIdx.x;
  const int tid = threadIdx.x;
  const int lane = tid & 63;
  const int w = __builtin_amdgcn_readfirstlane(tid >> 6);  // wave id
  const int v = w;  // vehicle for traj/term1/term3 phases

  const float* __restrict__ row = inputs + (size_t)n * kInRow;
  const float* __restrict__ pn = pre + (size_t)n * kPreStride;

  // Point-pair major trajectory: sh_p[v*65 + k] = (x,y,x,y) for h=2k,2k+1.
  // Row stride 65 float4 -> term2 window reads and term3 reads are
  // bank-balanced (start bank 4*(v2+j) mod 32, exactly 8 lanes per class).
  __shared__ float4 sh_p[kV * 65];
  __shared__ float sh_red[kV][5];

  const float R2 = pn[48];  // uniform -> s_load, zero VALU prep

  const float vx = rfl_f(row[4 * v + 0]);
  const float vy = rfl_f(row[4 * v + 1]);
  const float tx = rfl_f(row[4 * v + 2]);
  const float ty = rfl_f(row[4 * v + 3]);

  // Two headings per lane; 4 trans ops (unavoidable).
  const float2 th = ((const float2*)(pred + (size_t)n * (kV * kH)))[tid];
  v2f r01 = {th.x, th.y};
  r01 *= kInv2Pi;
  float c0 = __builtin_amdgcn_cosf(r01.x);
  float s0 = __builtin_amdgcn_sinf(r01.x);
  float c1 = __builtin_amdgcn_cosf(r01.y);
  float s1w = __builtin_amdgcn_sinf(r01.y);
  v2f step1 = {c1, s1w};  // step at h=2l+1
  step1 *= kStep;

  // Pair-sum scan: inclusive cumsum through h=2l+1.
  float Sx = wave_incl_scan((c0 + c1) * kStep);
  float Sy = wave_incl_scan((s0 + s1w) * kStep);
  const float px1 = vx + Sx, py1 = vy + Sy;              // h = 2l+1
  const float px0 = px1 - step1.x, py0 = py1 - step1.y;  // h = 2l

  sh_p[v * 65 + lane] = make_float4(px0, py0, px1, py1);

  const v2f pxp = {px0, px1};
  const v2f pyp = {py0, py1};

  // Term 1: distance to target (both points), packed diffs/squares.
  v2f t_dx = tx - pxp;
  v2f t_dy = ty - pyp;
  v2f t_d2 = __builtin_elementwise_fma(t_dy, t_dy, t_dx * t_dx);
  float s1 = __builtin_amdgcn_sqrtf(t_d2.x) + __builtin_amdgcn_sqrtf(t_d2.y);

  __syncthreads();  // sh_p visible

  // Term 3: inter-vehicle distance (v vs v+1, same h). v wave-uniform.
  float s3 = 0.f;
  int c3i = 0;
  if (v < kV - 1) {
    float4 t2 = sh_p[(v + 1) * 65 + lane];
    v2f ex = {t2.x, t2.z};
    v2f ey = {t2.y, t2.w};
    ex -= pxp;
    ey -= pyp;
    v2f e2 = __builtin_elementwise_fma(ey, ey, ex * ex);
    bool m0 = e2.x < kVehRadius * kVehRadius;
    bool m1 = e2.y < kVehRadius * kVehRadius;
    unsigned long long b0 = __ballot(m0);
    unsigned long long b1 = __ballot(m1);
    if (b0 | b1) {
      float i0 = __builtin_amdgcn_rsqf(e2.x);
      float i1 = __builtin_amdgcn_rsqf(e2.y);
      s3 = (m0 ? i0 : 0.f) + (m1 ? i1 : 0.f);
      c3i = (int)__popcll(b0) + (int)__popcll(b1);
    }
  }

  // Term 2 (h-window layout): lane = (v2, j); points h = 16w+2j, 16w+2j+1.
  const int v2i = lane >> 3;
  const int j = lane & 7;
  float4 q = sh_p[v2i * 65 + w * 8 + j];
  const v2f qx = {q.x, q.z};
  const v2f qy = {q.y, q.w};
  float s2 = 0.f;
  int c2i = 0;
  v2f q2 = __builtin_elementwise_fma(qy, qy, qx * qx);
  bool near = (q2.x < R2) || (q2.y < R2);
  if (__ballot(near)) {
#pragma unroll
    for (int o = 0; o < kO; ++o) {
      float oxo = pn[o];        // uniform s_loads, no prep VALU
      float oyo = pn[16 + o];
      float r2o = pn[32 + o];
      v2f dx = qx - oxo;
      v2f dy = qy - oyo;
      v2f d2 = __builtin_elementwise_fma(dy, dy, dx * dx);
      bool ma = d2.x < r2o;
      bool mb = d2.y < r2o;
      unsigned long long ba = __ballot(ma);
      unsigned long long bb = __ballot(mb);
      if (ba | bb) {
        float inva = __builtin_amdgcn_rsqf(d2.x);
        float invb = __builtin_amdgcn_rsqf(d2.y);
        s2 += (ma ? inva : 0.f) + (mb ? invb : 0.f);
        c2i += (int)__popcll(ba) + (int)__popcll(bb);
      }
    }
  }

  // Wave-reduce the 3 float sums (counts already wave-scalar), then 8 waves
  // combine through LDS; 5 threads store the block partials.
  float r1s = wave_incl_scan(s1);
  float r2s = wave_incl_scan(s2);
  float r3s = wave_incl_scan(s3);
  if (lane == 63) {
    sh_red[w][0] = r1s;
    sh_red[w][1] = r2s;
    sh_red[w][2] = r3s;
    sh_red[w][3] = (float)c2i;
    sh_red[w][4] = (float)c3i;
  }
  __syncthreads();
  if (tid < 5) {
    float acc = 0.f;
#pragma unroll
    for (int k = 0; k < kV; ++k) acc += sh_red[k][tid];
    partials[tid * kN + n] = acc;  // coalesced across blocks per-array
  }
}

// Single-block tree reduction over kN partials per accumulator (float4 loads).
__global__ __launch_bounds__(1024) void loss_final(
    const float* __restrict__ partials, float* __restrict__ out) {
  const int tid = threadIdx.x;
  const int lane = tid & 63;
  const int wave = tid >> 6;
  __shared__ float sh[16][5];
  float acc[5];
#pragma unroll
  for (int a = 0; a < 5; ++a) {
    const float4* pa = (const float4*)(partials + a * kN);  // 2048 float4
    float4 u = pa[tid];
    float4 w = pa[tid + 1024];
    acc[a] = (u.x + u.y) + (u.z + u.w) + (w.x + w.y) + (w.z + w.w);
  }
#pragma unroll
  for (int a = 0; a < 5; ++a) acc[a] = wave_incl_scan(acc[a]);
  if (lane == 63) {
#pragma unroll
    for (int a = 0; a < 5; ++a) sh[wave][a] = acc[a];
  }
  __syncthreads();
  if (tid == 0) {
    float t[5];
#pragma unroll
    for (int a = 0; a < 5; ++a) {
      float s = 0.f;
#pragma unroll
      for (int k = 0; k < 16; ++k) s += sh[k][a];
      t[a] = s;
    }
    float loss = t[0] * (1.0f / (float)(kN * kV * kH)) * kDistCost;
    if (t[3] > 0.f) loss += (t[1] / t[3]) * kObstCost;
    if (t[4] > 0.f) loss += (t[2] / t[4]) * kVehCost;
    out[0] = loss;
  }
}

extern "C" void kernel_launch(void* const* d_in, const int* in_sizes, int n_in,
                              void* d_out, int out_size, void* d_ws, size_t ws_size,
                              hipStream_t stream) {
  const float* pred = (const float*)d_in[0];     // (N, V, H, 1) f32
  const float* inputs = (const float*)d_in[1];   // (N, 80) f32
  float* pre = (float*)d_ws;                     // kN * 64 floats (2 MB)
  float* partials = pre + (size_t)kN * kPreStride;  // 5 * kN floats
  obst_pre<<<(kN * kO) / 256, 256, 0, stream>>>(inputs, pre);
  loss_main<<<kN, 512, 0, stream>>>(pred, inputs, pre, partials);
  loss_final<<<1, 1024, 0, stream>>>(partials, (float*)d_out);
}